// Round 2
// baseline (1026.150 us; speedup 1.0000x reference)
//
#include <hip/hip_runtime.h>
#include <hip/hip_bf16.h>

#define N_NODES 50000
#define N_EDGES 1600000
#define DIM 128
#define N_LAYERS 3
#define N_GRAPHS 128

// ---------------------------------------------------------------- utilities
// zero two int arrays (they are NOT contiguous — carver pads to 256B)
__global__ void zero2_kernel(int* __restrict__ a, int* __restrict__ b, int n) {
    int i = blockIdx.x * blockDim.x + threadIdx.x;
    if (i < n) { a[i] = 0; b[i] = 0; }
}

// ------------------------------------------------------------- CSR building
// deg histogram over destinations
__global__ void hist_kernel(const int* __restrict__ ei, int* __restrict__ deg, int ne) {
    int e = blockIdx.x * blockDim.x + threadIdx.x;
    if (e < ne) {
        int d = ei[N_EDGES + e];  // dst row
        atomicAdd(&deg[d], 1);
    }
}

// single-block exclusive scan over deg -> row_ptr, plus inv_deg
__global__ __launch_bounds__(1024) void scan_kernel(const int* __restrict__ deg,
                                                    int* __restrict__ row_ptr,
                                                    float* __restrict__ inv_deg,
                                                    int n) {
    __shared__ int sdata[1024];
    __shared__ int s_offset;
    int tid = threadIdx.x;
    if (tid == 0) { s_offset = 0; row_ptr[0] = 0; }
    __syncthreads();
    for (int base = 0; base < n; base += 1024) {
        int i = base + tid;
        int v = (i < n) ? deg[i] : 0;
        sdata[tid] = v;
        __syncthreads();
        // Hillis-Steele inclusive scan
        for (int off = 1; off < 1024; off <<= 1) {
            int t = (tid >= off) ? sdata[tid - off] : 0;
            __syncthreads();
            sdata[tid] += t;
            __syncthreads();
        }
        int incl = sdata[tid];
        int total = sdata[1023];
        if (i < n) {
            row_ptr[i + 1] = s_offset + incl;
            inv_deg[i] = (v > 0) ? 1.0f / (float)v : 0.0f;
        }
        __syncthreads();
        if (tid == 0) s_offset += total;
        __syncthreads();
    }
}

__global__ void fill_csr_kernel(const int* __restrict__ ei,
                                const int* __restrict__ row_ptr,
                                int* __restrict__ fill,
                                int* __restrict__ csr, int ne) {
    int e = blockIdx.x * blockDim.x + threadIdx.x;
    if (e < ne) {
        int s = ei[e];
        int d = ei[N_EDGES + e];
        int pos = atomicAdd(&fill[d], 1);
        csr[row_ptr[d] + pos] = s;
    }
}

// ------------------------------------------------------------- aggregation
// one wave (64 lanes) per destination node; lane handles 2 features (float2)
__global__ __launch_bounds__(256) void agg_kernel(const float* __restrict__ x,
                                                  const int* __restrict__ csr,
                                                  const int* __restrict__ row_ptr,
                                                  const float* __restrict__ inv_deg,
                                                  float* __restrict__ agg, int n) {
    int gw = (blockIdx.x * blockDim.x + threadIdx.x) >> 6;  // global wave id = node
    int lane = threadIdx.x & 63;
    if (gw >= n) return;
    int e0 = row_ptr[gw];
    int e1 = row_ptr[gw + 1];
    const float2* xp = (const float2*)x;
    float ax = 0.f, ay = 0.f;
    for (int e = e0; e < e1; ++e) {
        int s = csr[e];
        float2 v = xp[(size_t)s * 64 + lane];
        ax += v.x; ay += v.y;
    }
    float w = inv_deg[gw];
    float2 o; o.x = ax * w; o.y = ay * w;
    ((float2*)agg)[(size_t)gw * 64 + lane] = o;
}

// ------------------------------------------------------------------- GEMM
// out = agg @ Wl + xin @ Wr + bias  (+ optional ReLU)
// out may alias agg (rows are staged to LDS before any write).
// 256 threads, 32 rows/block, per-thread 4 rows x 4 cols.
#define GR 32
__global__ __launch_bounds__(256) void gemm_kernel(const float* agg, const float* xin,
                                                   const float* __restrict__ Wl,
                                                   const float* __restrict__ Wr,
                                                   const float* __restrict__ bias,
                                                   float* out, int n, int do_relu) {
    __shared__ float sA[GR][DIM];
    __shared__ float sX[GR][DIM];
    const int tid = threadIdx.x;
    const int row0 = blockIdx.x * GR;

    for (int idx = tid; idx < GR * 32; idx += 256) {
        int r = idx >> 5;
        int c4 = idx & 31;
        int gr = row0 + r;
        float4 va = make_float4(0.f, 0.f, 0.f, 0.f);
        float4 vx = va;
        if (gr < n) {
            va = ((const float4*)agg)[(size_t)gr * 32 + c4];
            vx = ((const float4*)xin)[(size_t)gr * 32 + c4];
        }
        ((float4*)&sA[r][0])[c4] = va;
        ((float4*)&sX[r][0])[c4] = vx;
    }
    __syncthreads();

    const int jg = tid & 31;    // column group base (cols jg + 32*c)
    const int rg = tid >> 5;    // row group 0..7 (rows rg + 8*m)

    float acc[4][4];
#pragma unroll
    for (int m = 0; m < 4; m++)
#pragma unroll
        for (int c = 0; c < 4; c++) acc[m][c] = bias[jg + 32 * c];

    for (int k = 0; k < DIM; k += 4) {
        float wl[4][4], wr[4][4];  // [kk][c]
#pragma unroll
        for (int kk = 0; kk < 4; kk++)
#pragma unroll
            for (int c = 0; c < 4; c++) {
                wl[kk][c] = Wl[(k + kk) * DIM + jg + 32 * c];
                wr[kk][c] = Wr[(k + kk) * DIM + jg + 32 * c];
            }
#pragma unroll
        for (int m = 0; m < 4; m++) {
            int r = rg + 8 * m;
            float4 a  = *(const float4*)&sA[r][k];
            float4 xv = *(const float4*)&sX[r][k];
#pragma unroll
            for (int c = 0; c < 4; c++) {
                acc[m][c] += a.x * wl[0][c] + a.y * wl[1][c] + a.z * wl[2][c] + a.w * wl[3][c]
                           + xv.x * wr[0][c] + xv.y * wr[1][c] + xv.z * wr[2][c] + xv.w * wr[3][c];
            }
        }
    }

#pragma unroll
    for (int m = 0; m < 4; m++) {
        int gr = row0 + rg + 8 * m;
        if (gr < n) {
#pragma unroll
            for (int c = 0; c < 4; c++) {
                float v = acc[m][c];
                if (do_relu) v = fmaxf(v, 0.f);
                out[(size_t)gr * DIM + jg + 32 * c] = v;
            }
        }
    }
}

// ------------------------------------------------------------------- pool
// one block per graph; batch is sorted, binary-search segment bounds
__global__ __launch_bounds__(128) void pool_kernel(const float* __restrict__ x,
                                                   const int* __restrict__ batch,
                                                   float* __restrict__ out, int n) {
    int g = blockIdx.x;
    int j = threadIdx.x;
    int lo = 0, hi = n;
    while (lo < hi) { int mid = (lo + hi) >> 1; if (batch[mid] < g) lo = mid + 1; else hi = mid; }
    int start = lo;
    lo = 0; hi = n;
    while (lo < hi) { int mid = (lo + hi) >> 1; if (batch[mid] < g + 1) lo = mid + 1; else hi = mid; }
    int end = lo;
    float acc = 0.f;
    for (int i = start; i < end; ++i) acc += x[(size_t)i * DIM + j];
    out[(size_t)g * DIM + j] = acc;
}

// ---------------------------------------------------------------- launcher
extern "C" void kernel_launch(void* const* d_in, const int* in_sizes, int n_in,
                              void* d_out, int out_size, void* d_ws, size_t ws_size,
                              hipStream_t stream) {
    const float* x   = (const float*)d_in[0];
    const int*   ei  = (const int*)d_in[1];    // [2][N_EDGES]
    const int*   bat = (const int*)d_in[2];    // [N_NODES]
    const float* Wl  = (const float*)d_in[3];  // [3][128][128]
    const float* Wr  = (const float*)d_in[4];
    const float* b   = (const float*)d_in[5];  // [3][128]
    float* out = (float*)d_out;

    // workspace carve (all offsets 256B-aligned)
    char* ws = (char*)d_ws;
    size_t off = 0;
    auto carve = [&](size_t bytes) {
        void* p = ws + off;
        off += (bytes + 255) & ~(size_t)255;
        return p;
    };
    int*   deg     = (int*)carve(sizeof(int) * N_NODES);
    int*   fill    = (int*)carve(sizeof(int) * N_NODES);
    int*   row_ptr = (int*)carve(sizeof(int) * (N_NODES + 1));
    int*   csr     = (int*)carve(sizeof(int) * N_EDGES);
    float* inv_deg = (float*)carve(sizeof(float) * N_NODES);
    float* bufA    = (float*)carve(sizeof(float) * (size_t)N_NODES * DIM);
    float* bufB    = (float*)carve(sizeof(float) * (size_t)N_NODES * DIM);
    (void)ws_size; (void)in_sizes; (void)n_in; (void)out_size;

    // zero deg and fill at their TRUE carved addresses (256B pad between them
    // made the old "one contiguous zero" miss the tail of fill -> poisoned
    // atomic counters -> OOB csr writes -> GPU abort)
    zero2_kernel<<<(N_NODES + 255) / 256, 256, 0, stream>>>(deg, fill, N_NODES);
    hist_kernel<<<(N_EDGES + 255) / 256, 256, 0, stream>>>(ei, deg, N_EDGES);
    scan_kernel<<<1, 1024, 0, stream>>>(deg, row_ptr, inv_deg, N_NODES);
    fill_csr_kernel<<<(N_EDGES + 255) / 256, 256, 0, stream>>>(ei, row_ptr, fill, csr, N_EDGES);

    const int aggGrid  = (N_NODES * 64 + 255) / 256;
    const int gemmGrid = (N_NODES + GR - 1) / GR;

    // layer 0: x -> bufA (agg), gemm in-place into bufA
    agg_kernel<<<aggGrid, 256, 0, stream>>>(x, csr, row_ptr, inv_deg, bufA, N_NODES);
    gemm_kernel<<<gemmGrid, 256, 0, stream>>>(bufA, x, Wl + 0 * DIM * DIM, Wr + 0 * DIM * DIM,
                                              b + 0 * DIM, bufA, N_NODES, 1);
    // layer 1: bufA -> bufB
    agg_kernel<<<aggGrid, 256, 0, stream>>>(bufA, csr, row_ptr, inv_deg, bufB, N_NODES);
    gemm_kernel<<<gemmGrid, 256, 0, stream>>>(bufB, bufA, Wl + 1 * DIM * DIM, Wr + 1 * DIM * DIM,
                                              b + 1 * DIM, bufB, N_NODES, 1);
    // layer 2: bufB -> bufA (no relu)
    agg_kernel<<<aggGrid, 256, 0, stream>>>(bufB, csr, row_ptr, inv_deg, bufA, N_NODES);
    gemm_kernel<<<gemmGrid, 256, 0, stream>>>(bufA, bufB, Wl + 2 * DIM * DIM, Wr + 2 * DIM * DIM,
                                              b + 2 * DIM, bufA, N_NODES, 0);

    pool_kernel<<<N_GRAPHS, 128, 0, stream>>>(bufA, bat, out, N_NODES);
}

// Round 3
// 569.401 us; speedup vs baseline: 1.8022x; 1.8022x over previous
//
#include <hip/hip_runtime.h>
#include <hip/hip_bf16.h>

#define N_NODES 50000
#define N_EDGES 1600000
#define DIM 128
#define N_LAYERS 3
#define N_GRAPHS 128

// ------------------------------------------------------------ bf16 helpers
__device__ __forceinline__ float bfu2f(unsigned short u) {
    union { unsigned int i; float f; } c; c.i = ((unsigned int)u) << 16; return c.f;
}
__device__ __forceinline__ unsigned short f2bfu(float f) {
    __hip_bfloat16 h = __float2bfloat16(f);  // RNE
    return *reinterpret_cast<unsigned short*>(&h);
}

// ---------------------------------------------------------------- utilities
__global__ void zero2_kernel(int* __restrict__ a, int* __restrict__ b, int n) {
    int i = blockIdx.x * blockDim.x + threadIdx.x;
    if (i < n) { a[i] = 0; b[i] = 0; }
}

// x (f32) -> xb (bf16), vectorized
__global__ __launch_bounds__(256) void cvt_kernel(const float4* __restrict__ x,
                                                  ushort4* __restrict__ xb, int n4) {
    int i = blockIdx.x * blockDim.x + threadIdx.x;
    if (i < n4) {
        float4 v = x[i];
        ushort4 o;
        o.x = f2bfu(v.x); o.y = f2bfu(v.y); o.z = f2bfu(v.z); o.w = f2bfu(v.w);
        xb[i] = o;
    }
}

// ------------------------------------------------------------- CSR building
__global__ void hist_kernel(const int* __restrict__ ei, int* __restrict__ deg, int ne) {
    int e = blockIdx.x * blockDim.x + threadIdx.x;
    if (e < ne) atomicAdd(&deg[ei[N_EDGES + e]], 1);
}

// 3-phase parallel exclusive scan (replaces the 1-block serial scan)
__global__ __launch_bounds__(256) void scan_block_sums(const int* __restrict__ deg,
                                                       int* __restrict__ bsums, int n) {
    __shared__ int sd[256];
    int tid = threadIdx.x;
    int i = blockIdx.x * 256 + tid;
    sd[tid] = (i < n) ? deg[i] : 0;
    __syncthreads();
    for (int off = 1; off < 256; off <<= 1) {
        int t = (tid >= off) ? sd[tid - off] : 0;
        __syncthreads();
        sd[tid] += t;
        __syncthreads();
    }
    if (tid == 255) bsums[blockIdx.x] = sd[255];
}

__global__ __launch_bounds__(256) void scan_offsets(int* __restrict__ bsums, int nb) {
    __shared__ int sd[256];
    int tid = threadIdx.x;
    int v = (tid < nb) ? bsums[tid] : 0;
    sd[tid] = v;
    __syncthreads();
    for (int off = 1; off < 256; off <<= 1) {
        int t = (tid >= off) ? sd[tid - off] : 0;
        __syncthreads();
        sd[tid] += t;
        __syncthreads();
    }
    if (tid < nb) bsums[tid] = sd[tid] - v;  // exclusive
}

__global__ __launch_bounds__(256) void scan_write(const int* __restrict__ deg,
                                                  const int* __restrict__ bsums,
                                                  int* __restrict__ row_ptr,
                                                  float* __restrict__ inv_deg, int n) {
    __shared__ int sd[256];
    int tid = threadIdx.x;
    int i = blockIdx.x * 256 + tid;
    int v = (i < n) ? deg[i] : 0;
    sd[tid] = v;
    __syncthreads();
    for (int off = 1; off < 256; off <<= 1) {
        int t = (tid >= off) ? sd[tid - off] : 0;
        __syncthreads();
        sd[tid] += t;
        __syncthreads();
    }
    if (i < n) {
        row_ptr[i + 1] = bsums[blockIdx.x] + sd[tid];
        inv_deg[i] = (v > 0) ? 1.0f / (float)v : 0.0f;
    }
    if (i == 0) row_ptr[0] = 0;
}

__global__ void fill_csr_kernel(const int* __restrict__ ei,
                                const int* __restrict__ row_ptr,
                                int* __restrict__ fill,
                                int* __restrict__ csr, int ne) {
    int e = blockIdx.x * blockDim.x + threadIdx.x;
    if (e < ne) {
        int s = ei[e];
        int d = ei[N_EDGES + e];
        int pos = atomicAdd(&fill[d], 1);
        csr[row_ptr[d] + pos] = s;
    }
}

// ------------------------------------------------------------- aggregation
// one wave per destination node; lane handles 2 bf16 features (4B load);
// edge loop unrolled x4 for memory-level parallelism
__global__ __launch_bounds__(256) void agg_kernel(const ushort2* __restrict__ xb,
                                                  const int* __restrict__ csr,
                                                  const int* __restrict__ row_ptr,
                                                  const float* __restrict__ inv_deg,
                                                  ushort2* __restrict__ aggb, int n) {
    int gw = (blockIdx.x * blockDim.x + threadIdx.x) >> 6;
    int lane = threadIdx.x & 63;
    if (gw >= n) return;
    int e0 = row_ptr[gw];
    int e1 = row_ptr[gw + 1];
    float ax = 0.f, ay = 0.f;
    int e = e0;
    for (; e + 4 <= e1; e += 4) {
        int s0 = csr[e], s1 = csr[e + 1], s2 = csr[e + 2], s3 = csr[e + 3];
        ushort2 v0 = xb[(size_t)s0 * 64 + lane];
        ushort2 v1 = xb[(size_t)s1 * 64 + lane];
        ushort2 v2 = xb[(size_t)s2 * 64 + lane];
        ushort2 v3 = xb[(size_t)s3 * 64 + lane];
        ax += bfu2f(v0.x) + bfu2f(v1.x) + bfu2f(v2.x) + bfu2f(v3.x);
        ay += bfu2f(v0.y) + bfu2f(v1.y) + bfu2f(v2.y) + bfu2f(v3.y);
    }
    for (; e < e1; ++e) {
        ushort2 v = xb[(size_t)csr[e] * 64 + lane];
        ax += bfu2f(v.x);
        ay += bfu2f(v.y);
    }
    float w = inv_deg[gw];
    ushort2 o;
    o.x = f2bfu(ax * w);
    o.y = f2bfu(ay * w);
    aggb[(size_t)gw * 64 + lane] = o;
}

// ------------------------------------------------------------------- GEMM
// out = aggb @ Wl + xb @ Wr + bias (+ReLU). bf16 in; bf16 or f32 out.
#define GR 32
template <int OUT_BF16, int RELU>
__global__ __launch_bounds__(256) void gemm_kernel(const unsigned short* __restrict__ aggb,
                                                   const unsigned short* __restrict__ xb,
                                                   const float* __restrict__ Wl,
                                                   const float* __restrict__ Wr,
                                                   const float* __restrict__ bias,
                                                   unsigned short* __restrict__ outb,
                                                   float* __restrict__ outf, int n) {
    __shared__ float sA[GR][DIM];
    __shared__ float sX[GR][DIM];
    const int tid = threadIdx.x;
    const int row0 = blockIdx.x * GR;

    for (int idx = tid; idx < GR * 32; idx += 256) {
        int r = idx >> 5;
        int c4 = idx & 31;  // group of 4 features
        int gr = row0 + r;
        float4 va = make_float4(0.f, 0.f, 0.f, 0.f);
        float4 vx = va;
        if (gr < n) {
            ushort4 ua = ((const ushort4*)aggb)[(size_t)gr * 32 + c4];
            ushort4 ux = ((const ushort4*)xb)[(size_t)gr * 32 + c4];
            va = make_float4(bfu2f(ua.x), bfu2f(ua.y), bfu2f(ua.z), bfu2f(ua.w));
            vx = make_float4(bfu2f(ux.x), bfu2f(ux.y), bfu2f(ux.z), bfu2f(ux.w));
        }
        ((float4*)&sA[r][0])[c4] = va;
        ((float4*)&sX[r][0])[c4] = vx;
    }
    __syncthreads();

    const int jg = tid & 31;
    const int rg = tid >> 5;

    float acc[4][4];
#pragma unroll
    for (int m = 0; m < 4; m++)
#pragma unroll
        for (int c = 0; c < 4; c++) acc[m][c] = bias[jg + 32 * c];

    for (int k = 0; k < DIM; k += 4) {
        float wl[4][4], wr[4][4];
#pragma unroll
        for (int kk = 0; kk < 4; kk++)
#pragma unroll
            for (int c = 0; c < 4; c++) {
                wl[kk][c] = Wl[(k + kk) * DIM + jg + 32 * c];
                wr[kk][c] = Wr[(k + kk) * DIM + jg + 32 * c];
            }
#pragma unroll
        for (int m = 0; m < 4; m++) {
            int r = rg + 8 * m;
            float4 a  = *(const float4*)&sA[r][k];
            float4 xv = *(const float4*)&sX[r][k];
#pragma unroll
            for (int c = 0; c < 4; c++) {
                acc[m][c] += a.x * wl[0][c] + a.y * wl[1][c] + a.z * wl[2][c] + a.w * wl[3][c]
                           + xv.x * wr[0][c] + xv.y * wr[1][c] + xv.z * wr[2][c] + xv.w * wr[3][c];
            }
        }
    }

#pragma unroll
    for (int m = 0; m < 4; m++) {
        int gr = row0 + rg + 8 * m;
        if (gr < n) {
#pragma unroll
            for (int c = 0; c < 4; c++) {
                float v = acc[m][c];
                if (RELU) v = fmaxf(v, 0.f);
                if (OUT_BF16) outb[(size_t)gr * DIM + jg + 32 * c] = f2bfu(v);
                else          outf[(size_t)gr * DIM + jg + 32 * c] = v;
            }
        }
    }
}

// ------------------------------------------------------------------- pool
// one 1024-thread block per graph; 8 row-lanes per feature, LDS tree combine
__global__ __launch_bounds__(1024) void pool_kernel(const float* __restrict__ xf,
                                                    const int* __restrict__ batch,
                                                    float* __restrict__ out) {
    __shared__ float red[8][DIM];
    int g = blockIdx.x;
    int j = threadIdx.x & 127;
    int rl = threadIdx.x >> 7;  // 0..7
    int lo = 0, hi = N_NODES;
    while (lo < hi) { int m = (lo + hi) >> 1; if (batch[m] < g) lo = m + 1; else hi = m; }
    int start = lo;
    lo = 0; hi = N_NODES;
    while (lo < hi) { int m = (lo + hi) >> 1; if (batch[m] < g + 1) lo = m + 1; else hi = m; }
    int end = lo;
    float acc = 0.f;
    for (int r = start + rl; r < end; r += 8) acc += xf[(size_t)r * DIM + j];
    red[rl][j] = acc;
    __syncthreads();
    if (rl == 0) {
        float s = ((red[0][j] + red[1][j]) + (red[2][j] + red[3][j]))
                + ((red[4][j] + red[5][j]) + (red[6][j] + red[7][j]));
        out[g * DIM + j] = s;
    }
}

// ---------------------------------------------------------------- launcher
extern "C" void kernel_launch(void* const* d_in, const int* in_sizes, int n_in,
                              void* d_out, int out_size, void* d_ws, size_t ws_size,
                              hipStream_t stream) {
    const float* x   = (const float*)d_in[0];
    const int*   ei  = (const int*)d_in[1];
    const int*   bat = (const int*)d_in[2];
    const float* Wl  = (const float*)d_in[3];
    const float* Wr  = (const float*)d_in[4];
    const float* b   = (const float*)d_in[5];
    float* out = (float*)d_out;

    char* ws = (char*)d_ws;
    size_t off = 0;
    auto carve = [&](size_t bytes) {
        void* p = ws + off;
        off += (bytes + 255) & ~(size_t)255;
        return p;
    };
    int*   deg     = (int*)carve(sizeof(int) * N_NODES);
    int*   fill    = (int*)carve(sizeof(int) * N_NODES);
    int*   row_ptr = (int*)carve(sizeof(int) * (N_NODES + 1));
    int*   bsums   = (int*)carve(sizeof(int) * 256);
    int*   csr     = (int*)carve(sizeof(int) * N_EDGES);
    float* inv_deg = (float*)carve(sizeof(float) * N_NODES);
    unsigned short* xb   = (unsigned short*)carve(2ull * N_NODES * DIM);
    unsigned short* actA = (unsigned short*)carve(2ull * N_NODES * DIM);
    unsigned short* actB = (unsigned short*)carve(2ull * N_NODES * DIM);
    unsigned short* aggb = (unsigned short*)carve(2ull * N_NODES * DIM);
    float* finalf = (float*)carve(sizeof(float) * (size_t)N_NODES * DIM);
    (void)ws_size; (void)in_sizes; (void)n_in; (void)out_size;

    const int nBlkN = (N_NODES + 255) / 256;        // 196
    const int nBlkE = (N_EDGES + 255) / 256;        // 6250
    const int n4    = N_NODES * DIM / 4;            // 1.6M float4s

    zero2_kernel<<<nBlkN, 256, 0, stream>>>(deg, fill, N_NODES);
    cvt_kernel<<<(n4 + 255) / 256, 256, 0, stream>>>((const float4*)x, (ushort4*)xb, n4);
    hist_kernel<<<nBlkE, 256, 0, stream>>>(ei, deg, N_EDGES);
    scan_block_sums<<<nBlkN, 256, 0, stream>>>(deg, bsums, N_NODES);
    scan_offsets<<<1, 256, 0, stream>>>(bsums, nBlkN);
    scan_write<<<nBlkN, 256, 0, stream>>>(deg, bsums, row_ptr, inv_deg, N_NODES);
    fill_csr_kernel<<<nBlkE, 256, 0, stream>>>(ei, row_ptr, fill, csr, N_EDGES);

    const int aggGrid  = (N_NODES * 64 + 255) / 256;   // 12500
    const int gemmGrid = (N_NODES + GR - 1) / GR;      // 1563

    // layer 0
    agg_kernel<<<aggGrid, 256, 0, stream>>>((const ushort2*)xb, csr, row_ptr, inv_deg,
                                            (ushort2*)aggb, N_NODES);
    gemm_kernel<1, 1><<<gemmGrid, 256, 0, stream>>>(aggb, xb, Wl, Wr, b, actA, nullptr, N_NODES);
    // layer 1
    agg_kernel<<<aggGrid, 256, 0, stream>>>((const ushort2*)actA, csr, row_ptr, inv_deg,
                                            (ushort2*)aggb, N_NODES);
    gemm_kernel<1, 1><<<gemmGrid, 256, 0, stream>>>(aggb, actA, Wl + DIM * DIM, Wr + DIM * DIM,
                                                    b + DIM, actB, nullptr, N_NODES);
    // layer 2 (f32 out, no relu)
    agg_kernel<<<aggGrid, 256, 0, stream>>>((const ushort2*)actB, csr, row_ptr, inv_deg,
                                            (ushort2*)aggb, N_NODES);
    gemm_kernel<0, 0><<<gemmGrid, 256, 0, stream>>>(aggb, actB, Wl + 2 * DIM * DIM,
                                                    Wr + 2 * DIM * DIM, b + 2 * DIM,
                                                    nullptr, finalf, N_NODES);

    pool_kernel<<<N_GRAPHS, 1024, 0, stream>>>(finalf, bat, out);
}